// Round 2
// 417.152 us; speedup vs baseline: 1.0196x; 1.0196x over previous
//
#include <hip/hip_runtime.h>

#define NB   2000   // N
#define HH   4      // heads
#define KK   20     // topk
#define KP   2048   // padded K (j) dim for GEMM
#define GA   4      // rows per k_scores_topk block
#define EPSF 1e-8f

typedef unsigned short ushort;
typedef unsigned long long ull;
using short8   = __attribute__((ext_vector_type(8))) short;
using floatx4  = __attribute__((ext_vector_type(4))) float;
using ushortx4 = __attribute__((ext_vector_type(4))) unsigned short;
using ushortx8 = __attribute__((ext_vector_type(8))) unsigned short;

__device__ inline ushort f2bf(float f) {
    unsigned u = __builtin_bit_cast(unsigned, f);
    u += 0x7fffu + ((u >> 16) & 1u);   // round-to-nearest-even
    return (ushort)(u >> 16);
}

__device__ __forceinline__ void gload_lds16(const ushort* g, ushort* l) {
    __builtin_amdgcn_global_load_lds(
        (const __attribute__((address_space(1))) void*)g,
        (__attribute__((address_space(3))) void*)l, 16, 0, 0);
}

// VALU-only DPP max step: x = max(x, dpp_move(x, CTRL)). Invalid source
// lanes keep old (=x), which is identity for max.
template<int CTRL>
__device__ __forceinline__ float dppmax(float x) {
    int xi = __builtin_bit_cast(int, x);
    int yi = __builtin_amdgcn_update_dpp(xi, xi, CTRL, 0xF, 0xF, false);
    return fmaxf(x, __builtin_bit_cast(float, yi));
}

// After this chain lane 63 holds the wave-wide max (gfx9 wave64 pattern:
// row_shr 1/2/4/8 within rows of 16, then row_bcast15 / row_bcast31).
__device__ __forceinline__ float wavemax63(float x) {
    x = dppmax<0x111>(x);   // row_shr:1
    x = dppmax<0x112>(x);   // row_shr:2
    x = dppmax<0x114>(x);   // row_shr:4
    x = dppmax<0x118>(x);   // row_shr:8
    x = dppmax<0x142>(x);   // row_bcast:15
    x = dppmax<0x143>(x);   // row_bcast:31
    return x;
}

#define COMP(v,i) ((i)==0?(v).x:(i)==1?(v).y:(i)==2?(v).z:(v).w)

// ---------------------------------------------------------------------------
// Kernel 1 (fused): scores + top-20 in score domain for GA=4 rows of one head.
// Wave w owns cols mbase = w*512 + lane*8. Selection: rounds are the OUTER
// loop and the 4 rows' reductions are interleaved (4 independent dep chains);
// cross-lane max uses a VALU-only DPP chain + v_readlane broadcast instead of
// ds_swizzle shfl_xor (the 6-deep ds_swizzle dependent chain was the latency
// bottleneck: VALUBusy 53%, no roofline engaged). Winner semantics unchanged:
// ballot on lm==M, lowest lane = lowest global idx; exact jax.lax.top_k
// tiebreak via packed u64 (valbits<<32 | ~idx) in the 4-list merge.
// ---------------------------------------------------------------------------
__global__ __launch_bounds__(256) void k_scores_topk(
    const float* __restrict__ e1, const float* __restrict__ e2,
    const float* __restrict__ temperature,
    int* __restrict__ topk_idx, float* __restrict__ topk_val)
{
    const int h  = blockIdx.y;
    const int n0 = blockIdx.x * GA;
    const int t  = threadIdx.x;
    const int w  = t >> 6, lane = t & 63;

    __shared__ float e1s[GA][64];
    __shared__ float red[GA][4];
    __shared__ ull   lists[4][GA][KK + 1];
    __shared__ float selpv[GA][KK];
    __shared__ int   seli[GA][KK];
    __shared__ float ssum[GA];

    e1s[t >> 6][t & 63] = e1[(size_t)(h * NB + n0 + (t >> 6)) * 64 + (t & 63)];
    __syncthreads();

    const float rtemp = 1.f / temperature[h];
    const float* __restrict__ e2h = e2 + (size_t)h * 64 * NB;

    const int  mbase = w * 512 + lane * 8;
    const bool valid = (mbase < NB);            // all-8-or-none (NB%8==0)
    const int  mload = valid ? mbase : (NB - 8);

    float acc[GA][8];
#pragma unroll
    for (int r = 0; r < GA; r++)
#pragma unroll
        for (int k = 0; k < 8; k++) acc[r][k] = 0.f;

    for (int d4 = 0; d4 < 64; d4 += 4) {
        float4 ev0 = *(const float4*)&e1s[0][d4];
        float4 ev1 = *(const float4*)&e1s[1][d4];
        float4 ev2 = *(const float4*)&e1s[2][d4];
        float4 ev3 = *(const float4*)&e1s[3][d4];
#pragma unroll
        for (int dd = 0; dd < 4; dd++) {
            const float* __restrict__ row = e2h + (size_t)(d4 + dd) * NB + mload;
            float4 a = *(const float4*)row;
            float4 b = *(const float4*)(row + 4);
            float f0 = COMP(ev0, dd), f1 = COMP(ev1, dd);
            float f2 = COMP(ev2, dd), f3 = COMP(ev3, dd);
            acc[0][0] += f0*a.x; acc[0][1] += f0*a.y; acc[0][2] += f0*a.z; acc[0][3] += f0*a.w;
            acc[0][4] += f0*b.x; acc[0][5] += f0*b.y; acc[0][6] += f0*b.z; acc[0][7] += f0*b.w;
            acc[1][0] += f1*a.x; acc[1][1] += f1*a.y; acc[1][2] += f1*a.z; acc[1][3] += f1*a.w;
            acc[1][4] += f1*b.x; acc[1][5] += f1*b.y; acc[1][6] += f1*b.z; acc[1][7] += f1*b.w;
            acc[2][0] += f2*a.x; acc[2][1] += f2*a.y; acc[2][2] += f2*a.z; acc[2][3] += f2*a.w;
            acc[2][4] += f2*b.x; acc[2][5] += f2*b.y; acc[2][6] += f2*b.z; acc[2][7] += f2*b.w;
            acc[3][0] += f3*a.x; acc[3][1] += f3*a.y; acc[3][2] += f3*a.z; acc[3][3] += f3*a.w;
            acc[3][4] += f3*b.x; acc[3][5] += f3*b.y; acc[3][6] += f3*b.z; acc[3][7] += f3*b.w;
        }
    }

    // tv = relu(acc)*rtemp ; invalid tail lanes -> -1 sentinel (< any valid tv)
#pragma unroll
    for (int r = 0; r < GA; r++) {
        float tvm = -1.f;
#pragma unroll
        for (int k = 0; k < 8; k++) {
            float v = valid ? fmaxf(acc[r][k], 0.f) * rtemp : -1.f;
            acc[r][k] = v;
            tvm = fmaxf(tvm, v);
        }
        tvm = wavemax63(tvm);
        if (lane == 63) red[r][w] = tvm;   // slice max (for exp shift)
    }

    // running per-lane local argmax for each row (strict > keeps lowest k)
    float lm[GA]; int ak[GA];
#pragma unroll
    for (int r = 0; r < GA; r++) {
        float l = acc[r][0]; int a = 0;
#pragma unroll
        for (int k = 1; k < 8; k++)
            if (acc[r][k] > l) { l = acc[r][k]; a = k; }
        lm[r] = l; ak[r] = a;
    }

    // selection: 20 rounds; per round all 4 rows' DPP chains interleaved
    for (int round = 0; round < KK; round++) {
        float M[GA];
#pragma unroll
        for (int r = 0; r < GA; r++) M[r] = lm[r];
#pragma unroll
        for (int r = 0; r < GA; r++) M[r] = dppmax<0x111>(M[r]);
#pragma unroll
        for (int r = 0; r < GA; r++) M[r] = dppmax<0x112>(M[r]);
#pragma unroll
        for (int r = 0; r < GA; r++) M[r] = dppmax<0x114>(M[r]);
#pragma unroll
        for (int r = 0; r < GA; r++) M[r] = dppmax<0x118>(M[r]);
#pragma unroll
        for (int r = 0; r < GA; r++) M[r] = dppmax<0x142>(M[r]);
#pragma unroll
        for (int r = 0; r < GA; r++) M[r] = dppmax<0x143>(M[r]);
#pragma unroll
        for (int r = 0; r < GA; r++)
            M[r] = __builtin_bit_cast(float,
                     __builtin_amdgcn_readlane(__builtin_bit_cast(int, M[r]), 63));
#pragma unroll
        for (int r = 0; r < GA; r++) {
            ull ball = __ballot(lm[r] == M[r]);
            int wl   = __ffsll(ball) - 1;       // lowest lane = lowest global idx
            if (lane == wl) {
                int gidx = mbase + ak[r];
                lists[w][r][round] =
                    ((ull)__float_as_uint(M[r]) << 32) | (unsigned)~gidx;
#pragma unroll
                for (int k = 0; k < 8; k++) if (k == ak[r]) acc[r][k] = -2.f;
                float l = acc[r][0]; int a = 0;
#pragma unroll
                for (int k = 1; k < 8; k++)
                    if (acc[r][k] > l) { l = acc[r][k]; a = k; }
                lm[r] = l; ak[r] = a;
            }
        }
    }
#pragma unroll
    for (int r = 0; r < GA; r++)
        if (lane == 0) lists[w][r][KK] = 0ULL;  // merge sentinel
    __syncthreads();

    // merge 4 sorted lists per row; lanes 0..3 of wave 0 handle one row each
    if (t < GA) {
        const int r = t;
        float mx = fmaxf(fmaxf(red[r][0], red[r][1]), fmaxf(red[r][2], red[r][3]));
        int p0 = 0, p1 = 0, p2 = 0, p3 = 0;
        ull h0 = lists[0][r][0], h1 = lists[1][r][0];
        ull h2 = lists[2][r][0], h3 = lists[3][r][0];
        float ss = 0.f;
        for (int q = 0; q < KK; q++) {
            ull a_ = h0 >= h1 ? h0 : h1; int wa = h0 >= h1 ? 0 : 1;
            ull b_ = h2 >= h3 ? h2 : h3; int wb = h2 >= h3 ? 2 : 3;
            ull bk = a_ >= b_ ? a_ : b_; int bw = a_ >= b_ ? wa : wb;
            float tvv = __uint_as_float((unsigned)(bk >> 32));
            float pv  = __expf(tvv - mx);
            selpv[r][q] = pv;
            seli[r][q]  = (int)~(unsigned)bk;
            ss += pv;
            if      (bw == 0) h0 = lists[0][r][++p0];
            else if (bw == 1) h1 = lists[1][r][++p1];
            else if (bw == 2) h2 = lists[2][r][++p2];
            else              h3 = lists[3][r][++p3];
        }
        ssum[r] = ss;
    }
    __syncthreads();

    if (t < GA * KK) {
        int r = t / KK, q = t % KK;
        int o = (h * NB + n0 + r) * KK + q;
        topk_idx[o] = seli[r][q];
        topk_val[o] = selpv[r][q] / (ssum[r] + EPSF);
    }
}

// ---------------------------------------------------------------------------
// Kernel 2: final_adj row i; writes dense fp32 fadj (output) and scatters
// nonzeros into bf16 A-matrix faT_b[m=i][k=j] (pre-zeroed, K padded to 2048).
// ---------------------------------------------------------------------------
__global__ __launch_bounds__(256) void k_final_adj(
    const int* __restrict__ topk_idx, const float* __restrict__ topk_val,
    const float* __restrict__ ew1, const float* __restrict__ eb1,
    const float* __restrict__ ew2, const float* __restrict__ eb2,
    float* __restrict__ fadj_out, ushort* __restrict__ faT_b)
{
    const int i = blockIdx.x;
    const int t = threadIdx.x;

    __shared__ float rows[HH][NB];
    __shared__ float w1[32];
    __shared__ float b1[8];
    __shared__ float w2[8];
    __shared__ float b2v;

    for (int k = t; k < HH * NB; k += 256) ((float*)rows)[k] = 0.f;
    if (t < 32) w1[t] = ew1[t];
    if (t < 8)  { b1[t] = eb1[t]; w2[t] = ew2[t]; }
    if (t == 0) b2v = eb2[0];
    __syncthreads();

    if (t < HH * KK) {
        int h = t / KK, r = t % KK;
        int o = (h * NB + i) * KK + r;
        rows[h][topk_idx[o]] = topk_val[o];
    }
    __syncthreads();

#pragma unroll
    for (int k = 0; k < 8; k++) {
        int j = k * 256 + t;
        if (j < NB) {
            float f0 = rows[0][j], f1 = rows[1][j], f2 = rows[2][j], f3 = rows[3][j];
            float mean = (f0 + f1 + f2 + f3) * 0.25f;
            float outv = 0.f;
            if (mean > 0.f) {
                float ewv = b2v;
#pragma unroll
                for (int c = 0; c < 8; c++) {
                    float hid = f0 * w1[c] + f1 * w1[8 + c] + f2 * w1[16 + c] + f3 * w1[24 + c] + b1[c];
                    hid = fmaxf(hid, 0.f);
                    ewv += hid * w2[c];
                }
                float sig = 1.f / (1.f + expf(-ewv));
                outv = sig * mean;
                faT_b[(size_t)j * KP + i] = f2bf(outv);  // A[m=i][k=j] scatter
            }
            fadj_out[(size_t)i * NB + j] = outv;
        }
    }
}

// ---------------------------------------------------------------------------
// Kernel 3: support S_b[j][bl*64+d] (bf16, j-major) = x[b,j,l,:] @ W
// ---------------------------------------------------------------------------
__global__ __launch_bounds__(256) void k_support(
    const float* __restrict__ x, const float* __restrict__ w,
    ushort* __restrict__ S_b)
{
    const int j = blockIdx.x;
    const int t = threadIdx.x;

    __shared__ float xs[128 * 65];
    __shared__ float ws[64 * 64];

    for (int k = t; k < 4096; k += 256) ws[k] = w[k];
    for (int idx = t; idx < 8192; idx += 256) {
        int b_ = idx >> 11, rem = idx & 2047;
        int bl = (b_ << 5) + (rem >> 6), dd = rem & 63;
        xs[bl * 65 + dd] = x[(size_t)b_ * 4096000 + (size_t)j * 2048 + rem];
    }
    __syncthreads();

    const int dq = t & 15;
    const int g  = t >> 4;
    float acc[8][4];
#pragma unroll
    for (int r = 0; r < 8; r++)
#pragma unroll
        for (int c = 0; c < 4; c++) acc[r][c] = 0.f;

    for (int dd = 0; dd < 64; dd++) {
        float4 w4 = *(const float4*)&ws[dd * 64 + dq * 4];
#pragma unroll
        for (int r = 0; r < 8; r++) {
            float xv = xs[(g * 8 + r) * 65 + dd];
            acc[r][0] += xv * w4.x;
            acc[r][1] += xv * w4.y;
            acc[r][2] += xv * w4.z;
            acc[r][3] += xv * w4.w;
        }
    }

#pragma unroll
    for (int r = 0; r < 8; r++) {
        int bl = g * 8 + r;
        ushortx4 v;
        v.x = f2bf(acc[r][0]); v.y = f2bf(acc[r][1]);
        v.z = f2bf(acc[r][2]); v.w = f2bf(acc[r][3]);
        *(ushortx4*)&S_b[(size_t)j * 8192 + bl * 64 + dq * 4] = v;
    }
}

// ---------------------------------------------------------------------------
// Kernel 4: transpose S_b[j][c] (2000x8192 bf16) -> ST[c][j] (8192xKP bf16),
// zero-padding j in [2000,2048). 64x64 tiles via LDS.
// ---------------------------------------------------------------------------
__global__ __launch_bounds__(256) void k_transpose(
    const ushort* __restrict__ S_b, ushort* __restrict__ ST)
{
    const int jt = blockIdx.x;   // 0..31
    const int ct = blockIdx.y;   // 0..127
    const int t  = threadIdx.x;

    __shared__ ushort tile[64 * 65];

#pragma unroll
    for (int p = 0; p < 4; p++) {
        int q = p * 256 + t;
        int row = q >> 4, seg = q & 15;
        int j = jt * 64 + row;
        ushort v0 = 0, v1 = 0, v2 = 0, v3 = 0;
        if (j < NB) {
            const ushort* src = &S_b[(size_t)j * 8192 + ct * 64 + seg * 4];
            v0 = src[0]; v1 = src[1]; v2 = src[2]; v3 = src[3];
        }
        ushort* dst = &tile[row * 65 + seg * 4];
        dst[0] = v0; dst[1] = v1; dst[2] = v2; dst[3] = v3;
    }
    __syncthreads();

#pragma unroll
    for (int p = 0; p < 2; p++) {
        int q = p * 256 + t;
        int rc = q >> 3, s = q & 7;
        ushortx8 o;
#pragma unroll
        for (int k = 0; k < 8; k++) o[k] = tile[(s * 8 + k) * 65 + rc];
        *(ushortx8*)&ST[(size_t)(ct * 64 + rc) * KP + jt * 64 + s * 8] = o;
    }
}

// ---------------------------------------------------------------------------
// Kernel 5: MFMA bf16 GEMM: out[i][c] = sum_j A[i][j] * B[c][j]
// global_load_lds width=16 staging (m97 ladder step). LDS image is lane-linear
// (wave-uniform base + lane*16), so the XOR swizzle g = dg ^ (row&7) is
// applied on the GLOBAL fetch side; frag ds_read_b128 then covers each bank
// once per 8-lane group (conflict-free, == stride-1 pattern permuted).
// ---------------------------------------------------------------------------
__global__ __launch_bounds__(256) void k_gemm(
    const ushort* __restrict__ A, const ushort* __restrict__ B,
    const float* __restrict__ bias, float* __restrict__ out)
{
    __shared__ ushort As[128 * 64];
    __shared__ ushort Bs[128 * 64];

    const int t    = threadIdx.x;
    const int lane = t & 63, wave = t >> 6;
    const int wm   = wave & 1, wn = wave >> 1;
    const int i0   = blockIdx.x * 128;
    const int c0   = blockIdx.y * 128;

    const int lr = lane >> 3;   // local row within 8-row chunk
    const int dg = lane & 7;    // LDS dest group (fixed by lane-linear DMA)

    floatx4 acc[4][4];
#pragma unroll
    for (int r = 0; r < 4; r++)
#pragma unroll
        for (int c = 0; c < 4; c++) acc[r][c] = (floatx4)(0.f);

    for (int kb = 0; kb < 32; kb++) {
        __syncthreads();
#pragma unroll
        for (int p = 0; p < 4; p++) {
            int rowb = p * 32 + wave * 8;           // chunk base row (mult of 8)
            int row  = rowb + lr;
            int g    = dg ^ lr;                     // row&7 == lr here
            const ushort* ga = &A[(size_t)(i0 + row) * KP + kb * 64 + g * 8];
            const ushort* gb = &B[(size_t)(c0 + row) * KP + kb * 64 + g * 8];
            gload_lds16(ga, &As[rowb * 64]);
            gload_lds16(gb, &Bs[rowb * 64]);
        }
        __syncthreads();   // compiler emits s_waitcnt vmcnt(0) before barrier

#pragma unroll
        for (int kk = 0; kk < 2; kk++) {
            short8 af[4], bf[4];
            const int gidx = kk * 4 + (lane >> 4);   // global k-group 0..7
            const int dsw  = gidx ^ (lane & 7);      // m&7 == lane&7 for frag rows
#pragma unroll
            for (int r = 0; r < 4; r++) {
                int m = wm * 64 + r * 16 + (lane & 15);
                af[r] = *(const short8*)&As[m * 64 + dsw * 8];
            }
#pragma unroll
            for (int c = 0; c < 4; c++) {
                int m = wn * 64 + c * 16 + (lane & 15);
                bf[c] = *(const short8*)&Bs[m * 64 + dsw * 8];
            }
#pragma unroll
            for (int r = 0; r < 4; r++)
#pragma unroll
                for (int c = 0; c < 4; c++)
                    acc[r][c] = __builtin_amdgcn_mfma_f32_16x16x32_bf16(af[r], bf[c], acc[r][c], 0, 0, 0);
        }
    }

    // epilogue: D layout col = lane&15, row = (lane>>4)*4 + reg  [m89-verified]
    const int mq = (lane >> 4) * 4;
    const int nn = lane & 15;
#pragma unroll
    for (int r = 0; r < 4; r++) {
#pragma unroll
        for (int c = 0; c < 4; c++) {
            int cg = c0 + wn * 64 + c * 16 + nn;
            float bv = bias[cg & 63];
            int b_ = cg >> 11, rem = cg & 2047;
            float* op = out + (size_t)b_ * 4096000 + rem;
#pragma unroll
            for (int rg = 0; rg < 4; rg++) {
                int i = i0 + wm * 64 + r * 16 + mq + rg;
                if (i < NB) op[(size_t)i * 2048] = acc[r][c][rg] + bv;
            }
        }
    }
}

// ---------------------------------------------------------------------------
extern "C" void kernel_launch(void* const* d_in, const int* in_sizes, int n_in,
                              void* d_out, int out_size, void* d_ws, size_t ws_size,
                              hipStream_t stream)
{
    const float* x           = (const float*)d_in[0];
    const float* e1          = (const float*)d_in[1];
    const float* e2          = (const float*)d_in[2];
    const float* temperature = (const float*)d_in[3];
    const float* ew1         = (const float*)d_in[4];
    const float* eb1         = (const float*)d_in[5];
    const float* ew2         = (const float*)d_in[6];
    const float* eb2         = (const float*)d_in[7];
    const float* weight      = (const float*)d_in[8];
    const float* bias        = (const float*)d_in[9];

    float* out  = (float*)d_out;            // (B,N,L,DOUT) = 16,384,000 floats
    float* fadj = out + 16384000;           // (N,N)        =  4,000,000 floats

    // workspace (no aliasing needed anymore; adjw eliminated):
    //   ST    bf16 8192xKP   = 33,554,432 B
    //   S_b   bf16 2000x8192 = 32,768,000 B
    //   faT_b bf16 KPxKP     =  8,388,608 B
    //   topk  idx+val        =  1,280,000 B      total ~76.0 MB
    ushort* ST       = (ushort*)d_ws;
    ushort* S_b      = ST + (size_t)8192 * KP;
    ushort* faT_b    = (ushort*)((char*)d_ws + 66322432u);
    int*    topk_idx = (int*)(faT_b + (size_t)KP * KP);
    float*  topk_val = (float*)(topk_idx + 160000);

    hipMemsetAsync(faT_b, 0, (size_t)KP * KP * sizeof(ushort), stream);

    k_scores_topk<<<dim3(NB / GA, HH), 256, 0, stream>>>(e1, e2, temperature,
                                                         topk_idx, topk_val);
    k_final_adj<<<NB, 256, 0, stream>>>(topk_idx, topk_val, ew1, eb1, ew2, eb2,
                                        fadj, faT_b);
    k_support<<<NB, 256, 0, stream>>>(x, weight, S_b);
    k_transpose<<<dim3(32, 128), 256, 0, stream>>>(S_b, ST);
    k_gemm<<<dim3(16, 64), 256, 0, stream>>>(faT_b, ST, bias, out);
}

// Round 3
// 393.848 us; speedup vs baseline: 1.0800x; 1.0592x over previous
//
#include <hip/hip_runtime.h>

#define NB   2000   // N
#define HH   4      // heads
#define KK   20     // topk
#define KP   2048   // padded K (j) dim for GEMM
#define GA   4      // rows per k_scores_topk block
#define EPSF 1e-8f

typedef unsigned short ushort;
typedef unsigned long long ull;
using short8   = __attribute__((ext_vector_type(8))) short;
using floatx4  = __attribute__((ext_vector_type(4))) float;
using ushortx4 = __attribute__((ext_vector_type(4))) unsigned short;
using ushortx8 = __attribute__((ext_vector_type(8))) unsigned short;

__device__ inline ushort f2bf(float f) {
    unsigned u = __builtin_bit_cast(unsigned, f);
    u += 0x7fffu + ((u >> 16) & 1u);   // round-to-nearest-even
    return (ushort)(u >> 16);
}

__device__ __forceinline__ void gload_lds16(const ushort* g, ushort* l) {
    __builtin_amdgcn_global_load_lds(
        (const __attribute__((address_space(1))) void*)g,
        (__attribute__((address_space(3))) void*)l, 16, 0, 0);
}

// VALU-only DPP max step: x = max(x, dpp_move(x, CTRL)). Invalid source
// lanes keep old (=x), which is identity for max.
template<int CTRL>
__device__ __forceinline__ float dppmax(float x) {
    int xi = __builtin_bit_cast(int, x);
    int yi = __builtin_amdgcn_update_dpp(xi, xi, CTRL, 0xF, 0xF, false);
    return fmaxf(x, __builtin_bit_cast(float, yi));
}

// After this chain lane 63 holds the wave-wide max (gfx9 wave64 pattern:
// row_shr 1/2/4/8 within rows of 16, then row_bcast15 / row_bcast31).
__device__ __forceinline__ float wavemax63(float x) {
    x = dppmax<0x111>(x);   // row_shr:1
    x = dppmax<0x112>(x);   // row_shr:2
    x = dppmax<0x114>(x);   // row_shr:4
    x = dppmax<0x118>(x);   // row_shr:8
    x = dppmax<0x142>(x);   // row_bcast:15
    x = dppmax<0x143>(x);   // row_bcast:31
    return x;
}

#define COMP(v,i) ((i)==0?(v).x:(i)==1?(v).y:(i)==2?(v).z:(v).w)

// ---------------------------------------------------------------------------
// Kernel 1 (fused): scores + top-20 in score domain for GA=4 rows of one head.
// RESTRUCTURED (this round): two temporal phases to cap register pressure.
// Evidence: dispatch VGPR_Count=36 is incompatible with the 32 live fp32
// accumulators + 16 ev + load regs the old single-phase layout needs
// (>=55 VGPRs) => the accumulators were in scratch or AGPRs with
// read/write round-trips, explaining the 2-3x gap between static VALU count
// (~45us) and measured VALU-issue time (~95us).
//   Phase 1 (8 waves, 512 thr): GEMM with only 16 acc regs/wave (wave owns
//     4 rows x 4 cols/lane, 1KB fully-coalesced float4 e2 loads); raw scores
//     -> LDS scoresS[4][2048].
//   Phase 2/3 (waves 0-3): selection BYTE-IDENTICAL to the previous version,
//     reading its 4x8 per-lane slice back from LDS. Same rounds, tiebreak
//     (ballot lowest-lane = lowest gidx; packed u64 valbits<<32|~idx merge),
//     same outputs.
// Total fmacs / loads / selection bodies / L2 traffic unchanged.
// ---------------------------------------------------------------------------
__global__ __launch_bounds__(512) void k_scores_topk(
    const float* __restrict__ e1, const float* __restrict__ e2,
    const float* __restrict__ temperature,
    int* __restrict__ topk_idx, float* __restrict__ topk_val)
{
    const int h  = blockIdx.y;
    const int n0 = blockIdx.x * GA;
    const int t  = threadIdx.x;
    const int w  = t >> 6, lane = t & 63;

    __shared__ float e1s[GA][64];
    __shared__ float scoresS[GA][2048];
    __shared__ float red[GA][4];
    __shared__ ull   lists[4][GA][KK + 1];
    __shared__ float selpv[GA][KK];
    __shared__ int   seli[GA][KK];
    __shared__ float ssum[GA];

    if (t < 256)
        e1s[t >> 6][t & 63] = e1[(size_t)(h * NB + n0 + (t >> 6)) * 64 + (t & 63)];
    __syncthreads();

    const float rtemp = 1.f / temperature[h];
    const float* __restrict__ e2h = e2 + (size_t)h * 64 * NB;

    // ---- phase 1: GEMM, 8 waves, 4 cols per lane (16 accumulators) ----
    {
        const int mb1 = w * 256 + lane * 4;           // this lane's 4 cols
        const int ml1 = (mb1 < NB) ? mb1 : (NB - 4);  // clamp tail (dup cols)

        float acc[GA][4];
#pragma unroll
        for (int r = 0; r < GA; r++)
#pragma unroll
            for (int c = 0; c < 4; c++) acc[r][c] = 0.f;

        for (int d4 = 0; d4 < 64; d4 += 4) {
            float4 ev0 = *(const float4*)&e1s[0][d4];
            float4 ev1 = *(const float4*)&e1s[1][d4];
            float4 ev2 = *(const float4*)&e1s[2][d4];
            float4 ev3 = *(const float4*)&e1s[3][d4];
#pragma unroll
            for (int dd = 0; dd < 4; dd++) {
                float4 a = *(const float4*)(e2h + (size_t)(d4 + dd) * NB + ml1);
                float f0 = COMP(ev0, dd), f1 = COMP(ev1, dd);
                float f2 = COMP(ev2, dd), f3 = COMP(ev3, dd);
                acc[0][0] += f0*a.x; acc[0][1] += f0*a.y; acc[0][2] += f0*a.z; acc[0][3] += f0*a.w;
                acc[1][0] += f1*a.x; acc[1][1] += f1*a.y; acc[1][2] += f1*a.z; acc[1][3] += f1*a.w;
                acc[2][0] += f2*a.x; acc[2][1] += f2*a.y; acc[2][2] += f2*a.z; acc[2][3] += f2*a.w;
                acc[3][0] += f3*a.x; acc[3][1] += f3*a.y; acc[3][2] += f3*a.z; acc[3][3] += f3*a.w;
            }
        }

#pragma unroll
        for (int r = 0; r < GA; r++) {
            float4 v; v.x = acc[r][0]; v.y = acc[r][1]; v.z = acc[r][2]; v.w = acc[r][3];
            *(float4*)&scoresS[r][mb1] = v;   // LDS slot by UNCLAMPED col; tail slots garbage, sentineled below
        }
    }
    __syncthreads();

    // ---- phases 2+3: selection, waves 0-3 only (identical semantics) ----
    if (w < 4) {
        const int  mbase = w * 512 + lane * 8;
        const bool valid = (mbase < NB);            // all-8-or-none (NB%8==0)

        float acc[GA][8];
#pragma unroll
        for (int r = 0; r < GA; r++) {
            float4 lo = *(const float4*)&scoresS[r][mbase];
            float4 hi = *(const float4*)&scoresS[r][mbase + 4];
            acc[r][0] = lo.x; acc[r][1] = lo.y; acc[r][2] = lo.z; acc[r][3] = lo.w;
            acc[r][4] = hi.x; acc[r][5] = hi.y; acc[r][6] = hi.z; acc[r][7] = hi.w;
        }

        // tv = relu(acc)*rtemp ; invalid tail lanes -> -1 sentinel (< any valid tv)
#pragma unroll
        for (int r = 0; r < GA; r++) {
            float tvm = -1.f;
#pragma unroll
            for (int k = 0; k < 8; k++) {
                float v = valid ? fmaxf(acc[r][k], 0.f) * rtemp : -1.f;
                acc[r][k] = v;
                tvm = fmaxf(tvm, v);
            }
            tvm = wavemax63(tvm);
            if (lane == 63) red[r][w] = tvm;   // slice max (for exp shift)
        }

        // running per-lane local argmax for each row (strict > keeps lowest k)
        float lm[GA]; int ak[GA];
#pragma unroll
        for (int r = 0; r < GA; r++) {
            float l = acc[r][0]; int a = 0;
#pragma unroll
            for (int k = 1; k < 8; k++)
                if (acc[r][k] > l) { l = acc[r][k]; a = k; }
            lm[r] = l; ak[r] = a;
        }

        // selection: 20 rounds; per round all 4 rows' DPP chains interleaved
        for (int round = 0; round < KK; round++) {
            float M[GA];
#pragma unroll
            for (int r = 0; r < GA; r++) M[r] = lm[r];
#pragma unroll
            for (int r = 0; r < GA; r++) M[r] = dppmax<0x111>(M[r]);
#pragma unroll
            for (int r = 0; r < GA; r++) M[r] = dppmax<0x112>(M[r]);
#pragma unroll
            for (int r = 0; r < GA; r++) M[r] = dppmax<0x114>(M[r]);
#pragma unroll
            for (int r = 0; r < GA; r++) M[r] = dppmax<0x118>(M[r]);
#pragma unroll
            for (int r = 0; r < GA; r++) M[r] = dppmax<0x142>(M[r]);
#pragma unroll
            for (int r = 0; r < GA; r++) M[r] = dppmax<0x143>(M[r]);
#pragma unroll
            for (int r = 0; r < GA; r++)
                M[r] = __builtin_bit_cast(float,
                         __builtin_amdgcn_readlane(__builtin_bit_cast(int, M[r]), 63));
#pragma unroll
            for (int r = 0; r < GA; r++) {
                ull ball = __ballot(lm[r] == M[r]);
                int wl   = __ffsll(ball) - 1;       // lowest lane = lowest global idx
                if (lane == wl) {
                    int gidx = mbase + ak[r];
                    lists[w][r][round] =
                        ((ull)__float_as_uint(M[r]) << 32) | (unsigned)~gidx;
#pragma unroll
                    for (int k = 0; k < 8; k++) if (k == ak[r]) acc[r][k] = -2.f;
                    float l = acc[r][0]; int a = 0;
#pragma unroll
                    for (int k = 1; k < 8; k++)
                        if (acc[r][k] > l) { l = acc[r][k]; a = k; }
                    lm[r] = l; ak[r] = a;
                }
            }
        }
#pragma unroll
        for (int r = 0; r < GA; r++)
            if (lane == 0) lists[w][r][KK] = 0ULL;  // merge sentinel
    }
    __syncthreads();

    // merge 4 sorted lists per row; lanes 0..3 of wave 0 handle one row each
    if (t < GA) {
        const int r = t;
        float mx = fmaxf(fmaxf(red[r][0], red[r][1]), fmaxf(red[r][2], red[r][3]));
        int p0 = 0, p1 = 0, p2 = 0, p3 = 0;
        ull h0 = lists[0][r][0], h1 = lists[1][r][0];
        ull h2 = lists[2][r][0], h3 = lists[3][r][0];
        float ss = 0.f;
        for (int q = 0; q < KK; q++) {
            ull a_ = h0 >= h1 ? h0 : h1; int wa = h0 >= h1 ? 0 : 1;
            ull b_ = h2 >= h3 ? h2 : h3; int wb = h2 >= h3 ? 2 : 3;
            ull bk = a_ >= b_ ? a_ : b_; int bw = a_ >= b_ ? wa : wb;
            float tvv = __uint_as_float((unsigned)(bk >> 32));
            float pv  = __expf(tvv - mx);
            selpv[r][q] = pv;
            seli[r][q]  = (int)~(unsigned)bk;
            ss += pv;
            if      (bw == 0) h0 = lists[0][r][++p0];
            else if (bw == 1) h1 = lists[1][r][++p1];
            else if (bw == 2) h2 = lists[2][r][++p2];
            else              h3 = lists[3][r][++p3];
        }
        ssum[r] = ss;
    }
    __syncthreads();

    if (t < GA * KK) {
        int r = t / KK, q = t % KK;
        int o = (h * NB + n0 + r) * KK + q;
        topk_idx[o] = seli[r][q];
        topk_val[o] = selpv[r][q] / (ssum[r] + EPSF);
    }
}

// ---------------------------------------------------------------------------
// Kernel 2: final_adj row i; writes dense fp32 fadj (output) and scatters
// nonzeros into bf16 A-matrix faT_b[m=i][k=j] (pre-zeroed, K padded to 2048).
// ---------------------------------------------------------------------------
__global__ __launch_bounds__(256) void k_final_adj(
    const int* __restrict__ topk_idx, const float* __restrict__ topk_val,
    const float* __restrict__ ew1, const float* __restrict__ eb1,
    const float* __restrict__ ew2, const float* __restrict__ eb2,
    float* __restrict__ fadj_out, ushort* __restrict__ faT_b)
{
    const int i = blockIdx.x;
    const int t = threadIdx.x;

    __shared__ float rows[HH][NB];
    __shared__ float w1[32];
    __shared__ float b1[8];
    __shared__ float w2[8];
    __shared__ float b2v;

    for (int k = t; k < HH * NB; k += 256) ((float*)rows)[k] = 0.f;
    if (t < 32) w1[t] = ew1[t];
    if (t < 8)  { b1[t] = eb1[t]; w2[t] = ew2[t]; }
    if (t == 0) b2v = eb2[0];
    __syncthreads();

    if (t < HH * KK) {
        int h = t / KK, r = t % KK;
        int o = (h * NB + i) * KK + r;
        rows[h][topk_idx[o]] = topk_val[o];
    }
    __syncthreads();

#pragma unroll
    for (int k = 0; k < 8; k++) {
        int j = k * 256 + t;
        if (j < NB) {
            float f0 = rows[0][j], f1 = rows[1][j], f2 = rows[2][j], f3 = rows[3][j];
            float mean = (f0 + f1 + f2 + f3) * 0.25f;
            float outv = 0.f;
            if (mean > 0.f) {
                float ewv = b2v;
#pragma unroll
                for (int c = 0; c < 8; c++) {
                    float hid = f0 * w1[c] + f1 * w1[8 + c] + f2 * w1[16 + c] + f3 * w1[24 + c] + b1[c];
                    hid = fmaxf(hid, 0.f);
                    ewv += hid * w2[c];
                }
                float sig = 1.f / (1.f + expf(-ewv));
                outv = sig * mean;
                faT_b[(size_t)j * KP + i] = f2bf(outv);  // A[m=i][k=j] scatter
            }
            fadj_out[(size_t)i * NB + j] = outv;
        }
    }
}

// ---------------------------------------------------------------------------
// Kernel 3: support S_b[j][bl*64+d] (bf16, j-major) = x[b,j,l,:] @ W
// ---------------------------------------------------------------------------
__global__ __launch_bounds__(256) void k_support(
    const float* __restrict__ x, const float* __restrict__ w,
    ushort* __restrict__ S_b)
{
    const int j = blockIdx.x;
    const int t = threadIdx.x;

    __shared__ float xs[128 * 65];
    __shared__ float ws[64 * 64];

    for (int k = t; k < 4096; k += 256) ws[k] = w[k];
    for (int idx = t; idx < 8192; idx += 256) {
        int b_ = idx >> 11, rem = idx & 2047;
        int bl = (b_ << 5) + (rem >> 6), dd = rem & 63;
        xs[bl * 65 + dd] = x[(size_t)b_ * 4096000 + (size_t)j * 2048 + rem];
    }
    __syncthreads();

    const int dq = t & 15;
    const int g  = t >> 4;
    float acc[8][4];
#pragma unroll
    for (int r = 0; r < 8; r++)
#pragma unroll
        for (int c = 0; c < 4; c++) acc[r][c] = 0.f;

    for (int dd = 0; dd < 64; dd++) {
        float4 w4 = *(const float4*)&ws[dd * 64 + dq * 4];
#pragma unroll
        for (int r = 0; r < 8; r++) {
            float xv = xs[(g * 8 + r) * 65 + dd];
            acc[r][0] += xv * w4.x;
            acc[r][1] += xv * w4.y;
            acc[r][2] += xv * w4.z;
            acc[r][3] += xv * w4.w;
        }
    }

#pragma unroll
    for (int r = 0; r < 8; r++) {
        int bl = g * 8 + r;
        ushortx4 v;
        v.x = f2bf(acc[r][0]); v.y = f2bf(acc[r][1]);
        v.z = f2bf(acc[r][2]); v.w = f2bf(acc[r][3]);
        *(ushortx4*)&S_b[(size_t)j * 8192 + bl * 64 + dq * 4] = v;
    }
}

// ---------------------------------------------------------------------------
// Kernel 4: transpose S_b[j][c] (2000x8192 bf16) -> ST[c][j] (8192xKP bf16),
// zero-padding j in [2000,2048). 64x64 tiles via LDS.
// ---------------------------------------------------------------------------
__global__ __launch_bounds__(256) void k_transpose(
    const ushort* __restrict__ S_b, ushort* __restrict__ ST)
{
    const int jt = blockIdx.x;   // 0..31
    const int ct = blockIdx.y;   // 0..127
    const int t  = threadIdx.x;

    __shared__ ushort tile[64 * 65];

#pragma unroll
    for (int p = 0; p < 4; p++) {
        int q = p * 256 + t;
        int row = q >> 4, seg = q & 15;
        int j = jt * 64 + row;
        ushort v0 = 0, v1 = 0, v2 = 0, v3 = 0;
        if (j < NB) {
            const ushort* src = &S_b[(size_t)j * 8192 + ct * 64 + seg * 4];
            v0 = src[0]; v1 = src[1]; v2 = src[2]; v3 = src[3];
        }
        ushort* dst = &tile[row * 65 + seg * 4];
        dst[0] = v0; dst[1] = v1; dst[2] = v2; dst[3] = v3;
    }
    __syncthreads();

#pragma unroll
    for (int p = 0; p < 2; p++) {
        int q = p * 256 + t;
        int rc = q >> 3, s = q & 7;
        ushortx8 o;
#pragma unroll
        for (int k = 0; k < 8; k++) o[k] = tile[(s * 8 + k) * 65 + rc];
        *(ushortx8*)&ST[(size_t)(ct * 64 + rc) * KP + jt * 64 + s * 8] = o;
    }
}

// ---------------------------------------------------------------------------
// Kernel 5: MFMA bf16 GEMM: out[i][c] = sum_j A[i][j] * B[c][j]
// global_load_lds width=16 staging (m97 ladder step). LDS image is lane-linear
// (wave-uniform base + lane*16), so the XOR swizzle g = dg ^ (row&7) is
// applied on the GLOBAL fetch side; frag ds_read_b128 then covers each bank
// once per 8-lane group (conflict-free, == stride-1 pattern permuted).
// ---------------------------------------------------------------------------
__global__ __launch_bounds__(256) void k_gemm(
    const ushort* __restrict__ A, const ushort* __restrict__ B,
    const float* __restrict__ bias, float* __restrict__ out)
{
    __shared__ ushort As[128 * 64];
    __shared__ ushort Bs[128 * 64];

    const int t    = threadIdx.x;
    const int lane = t & 63, wave = t >> 6;
    const int wm   = wave & 1, wn = wave >> 1;
    const int i0   = blockIdx.x * 128;
    const int c0   = blockIdx.y * 128;

    const int lr = lane >> 3;   // local row within 8-row chunk
    const int dg = lane & 7;    // LDS dest group (fixed by lane-linear DMA)

    floatx4 acc[4][4];
#pragma unroll
    for (int r = 0; r < 4; r++)
#pragma unroll
        for (int c = 0; c < 4; c++) acc[r][c] = (floatx4)(0.f);

    for (int kb = 0; kb < 32; kb++) {
        __syncthreads();
#pragma unroll
        for (int p = 0; p < 4; p++) {
            int rowb = p * 32 + wave * 8;           // chunk base row (mult of 8)
            int row  = rowb + lr;
            int g    = dg ^ lr;                     // row&7 == lr here
            const ushort* ga = &A[(size_t)(i0 + row) * KP + kb * 64 + g * 8];
            const ushort* gb = &B[(size_t)(c0 + row) * KP + kb * 64 + g * 8];
            gload_lds16(ga, &As[rowb * 64]);
            gload_lds16(gb, &Bs[rowb * 64]);
        }
        __syncthreads();   // compiler emits s_waitcnt vmcnt(0) before barrier

#pragma unroll
        for (int kk = 0; kk < 2; kk++) {
            short8 af[4], bf[4];
            const int gidx = kk * 4 + (lane >> 4);   // global k-group 0..7
            const int dsw  = gidx ^ (lane & 7);      // m&7 == lane&7 for frag rows
#pragma unroll
            for (int r = 0; r < 4; r++) {
                int m = wm * 64 + r * 16 + (lane & 15);
                af[r] = *(const short8*)&As[m * 64 + dsw * 8];
            }
#pragma unroll
            for (int c = 0; c < 4; c++) {
                int m = wn * 64 + c * 16 + (lane & 15);
                bf[c] = *(const short8*)&Bs[m * 64 + dsw * 8];
            }
#pragma unroll
            for (int r = 0; r < 4; r++)
#pragma unroll
                for (int c = 0; c < 4; c++)
                    acc[r][c] = __builtin_amdgcn_mfma_f32_16x16x32_bf16(af[r], bf[c], acc[r][c], 0, 0, 0);
        }
    }

    // epilogue: D layout col = lane&15, row = (lane>>4)*4 + reg  [m89-verified]
    const int mq = (lane >> 4) * 4;
    const int nn = lane & 15;
#pragma unroll
    for (int r = 0; r < 4; r++) {
#pragma unroll
        for (int c = 0; c < 4; c++) {
            int cg = c0 + wn * 64 + c * 16 + nn;
            float bv = bias[cg & 63];
            int b_ = cg >> 11, rem = cg & 2047;
            float* op = out + (size_t)b_ * 4096000 + rem;
#pragma unroll
            for (int rg = 0; rg < 4; rg++) {
                int i = i0 + wm * 64 + r * 16 + mq + rg;
                if (i < NB) op[(size_t)i * 2048] = acc[r][c][rg] + bv;
            }
        }
    }
}

// ---------------------------------------------------------------------------
extern "C" void kernel_launch(void* const* d_in, const int* in_sizes, int n_in,
                              void* d_out, int out_size, void* d_ws, size_t ws_size,
                              hipStream_t stream)
{
    const float* x           = (const float*)d_in[0];
    const float* e1          = (const float*)d_in[1];
    const float* e2          = (const float*)d_in[2];
    const float* temperature = (const float*)d_in[3];
    const float* ew1         = (const float*)d_in[4];
    const float* eb1         = (const float*)d_in[5];
    const float* ew2         = (const float*)d_in[6];
    const float* eb2         = (const float*)d_in[7];
    const float* weight      = (const float*)d_in[8];
    const float* bias        = (const float*)d_in[9];

    float* out  = (float*)d_out;            // (B,N,L,DOUT) = 16,384,000 floats
    float* fadj = out + 16384000;           // (N,N)        =  4,000,000 floats

    // workspace (no aliasing needed anymore; adjw eliminated):
    //   ST    bf16 8192xKP   = 33,554,432 B
    //   S_b   bf16 2000x8192 = 32,768,000 B
    //   faT_b bf16 KPxKP     =  8,388,608 B
    //   topk  idx+val        =  1,280,000 B      total ~76.0 MB
    ushort* ST       = (ushort*)d_ws;
    ushort* S_b      = ST + (size_t)8192 * KP;
    ushort* faT_b    = (ushort*)((char*)d_ws + 66322432u);
    int*    topk_idx = (int*)(faT_b + (size_t)KP * KP);
    float*  topk_val = (float*)(topk_idx + 160000);

    hipMemsetAsync(faT_b, 0, (size_t)KP * KP * sizeof(ushort), stream);

    k_scores_topk<<<dim3(NB / GA, HH), 512, 0, stream>>>(e1, e2, temperature,
                                                         topk_idx, topk_val);
    k_final_adj<<<NB, 256, 0, stream>>>(topk_idx, topk_val, ew1, eb1, ew2, eb2,
                                        fadj, faT_b);
    k_support<<<NB, 256, 0, stream>>>(x, weight, S_b);
    k_transpose<<<dim3(32, 128), 256, 0, stream>>>(S_b, ST);
    k_gemm<<<dim3(16, 64), 256, 0, stream>>>(faT_b, ST, bias, out);
}